// Round 8
// baseline (294.777 us; speedup 1.0000x reference)
//
#include <hip/hip_runtime.h>
#include <hip/hip_bf16.h>

// MQA B=4 T=2048 C=1024 H=16 D=64.
// R13: MQA-sharing round. R12 post-mortem: setprio hurt barrier-locked attn
// (-5.6us, m190 mechanism) -> removed. Real lever: K/V are shared across all
// 16 heads but every (qb,h) block re-staged them (512MB LDS traffic, 16x
// redundant). New attn block = 4 heads x 128 q-rows, 1024 threads/16 waves;
// wave w: head hg*4+(w>>2), q-rows (w&3)*32. K/V staged once per block for
// 4 heads (traffic /4); grid 256 = exactly 1 block/CU (no tail imbalance);
// LDS 96KB (KV dbuf 32K + 16x4K Ps); VGPR<=128 -> 4 waves/SIMD. Per-wave
// inner loop byte-identical to R10 (best measured). proj merge kept (neutral,
// one less dispatch). prep/gemm_fin unchanged. Math/rounding unchanged.

#define B_ 4
#define T_ 2048
#define C_ 1024
#define H_ 16
#define D_ 64
#define BT_ (B_*T_)
#define CS_ 0.1803368801111204f   // (1/sqrt(64)) * log2(e)

typedef short bfrag __attribute__((ext_vector_type(8)));   // 8 bf16
typedef float f32x4 __attribute__((ext_vector_type(4)));
typedef __bf16 bf2_t __attribute__((ext_vector_type(2)));

// Native casts: clang lowers f32->bf16 on gfx950 to v_cvt_pk_bf16_f32 (RNE).
static __device__ inline short f2bf(float f){
    union { __bf16 h; short s; } c; c.h = (__bf16)f;
    return c.s;
}
static __device__ inline unsigned pk2(float a, float b){
    union { bf2_t v; unsigned u; } c;
    c.v[0] = (__bf16)a; c.v[1] = (__bf16)b;
    return c.u;
}

#if __has_builtin(__builtin_amdgcn_global_load_lds)
#define GLL16(g,l) __builtin_amdgcn_global_load_lds(                              \
    (const __attribute__((address_space(1))) void*)(g),                           \
    (__attribute__((address_space(3))) void*)(l), 16, 0, 0)
#else
#define GLL16(g,l) (*(uint4*)(l) = *(const uint4*)(g))
#endif

#if __has_builtin(__builtin_amdgcn_exp2f)
#define EXP2(x) __builtin_amdgcn_exp2f(x)
#else
#define EXP2(x) __expf((x)*0.693147180559945f)
#endif

// ---------------- prep: weight transposes only ----------------------------
__global__ __launch_bounds__(256) void prep_kernel(
    const float* __restrict__ Wq, const float* __restrict__ Wk,
    const float* __restrict__ Wv, const float* __restrict__ Wp,
    short* __restrict__ WqT, short* __restrict__ WkT,
    short* __restrict__ WvT, short* __restrict__ WpT)
{
    int b2 = blockIdx.x, tid = threadIdx.x;
    __shared__ short Ls[64][65];
    const float* W; short* Wt; int N, idx;
    if (b2 < 256)      { W = Wq; Wt = WqT; N = 1024; idx = b2; }
    else if (b2 < 272) { W = Wk; Wt = WkT; N = 64;   idx = b2 - 256; }
    else if (b2 < 288) { W = Wv; Wt = WvT; N = 64;   idx = b2 - 272; }
    else               { W = Wp; Wt = WpT; N = 1024; idx = b2 - 288; }
    int nx = N >> 6;
    int n0 = (idx % nx) * 64, k0 = (idx / nx) * 64;
    {
        int kr = tid >> 2, c4 = (tid & 3) * 16;
        const float* g = W + (size_t)(k0 + kr) * N + n0 + c4;
        #pragma unroll
        for (int e = 0; e < 16; e++) Ls[kr][c4 + e] = f2bf(g[e]);
    }
    __syncthreads();
    {
        int nr = tid >> 2, kc = (tid & 3) * 16;
        __align__(16) short tmp[16];
        #pragma unroll
        for (int e = 0; e < 16; e++) tmp[e] = Ls[kc + e][nr];
        short* o = Wt + (size_t)(n0 + nr) * 1024 + k0 + kc;
        *(uint4*)(o)     = *(uint4*)tmp;
        *(uint4*)(o + 8) = *(uint4*)(tmp + 8);
    }
}

// ---------------- merged projections: blocks 0..511 qproj, 512..1023 kv ----
__global__ __launch_bounds__(256) void proj_kernel(
    const float* __restrict__ Aq, const float* __restrict__ Ksrc,
    const float* __restrict__ Vsrc,
    const short* __restrict__ WqT, const short* __restrict__ WkT,
    const short* __restrict__ WvT,
    short* __restrict__ Qp, short* __restrict__ Kfo, short* __restrict__ Vfo)
{
    __shared__ __align__(16) short lds[16384];   // 32 KB shared by both paths
    int bx = blockIdx.x, tid = threadIdx.x;
    int w = tid >> 6, lane = tid & 63;
    int quad = lane >> 4, l16 = lane & 15;

    if (bx < 512) {
        // ---------------- qproj path ----------------
        short* As = lds;            // 128 x 64, frag order
        short* Bs = lds + 8192;     // 128 x 64, frag order
        const int K = C_;
        int wm = (w >> 1) * 64, wn = (w & 1) * 64;
        int m0 = (bx >> 3) * 128, n0 = (bx & 7) * 128;

        const float* gA[8]; short* lA[8];
        #pragma unroll
        for (int i = 0; i < 8; i++) {
            int c = tid + 256 * i;            // float4-chunk id, 0..2047
            int row = c >> 4, fc = c & 15;    // 16 float4 per 64-col row
            gA[i] = Aq + (size_t)(m0 + row) * K + fc * 4;
            int m16 = row >> 4, l16r = row & 15;
            int ks = fc >> 3, q4 = (fc >> 1) & 3, e0 = (fc & 1) * 4;
            lA[i] = As + ((m16 * 2 + ks) * 64 + l16r * 4 + q4) * 8 + e0;
        }
        const short* gB[4]; short* lB[4];
        #pragma unroll
        for (int i = 0; i < 4; i++) {
            int c = tid + 256 * i;
            int row = ((c >> 7) << 4) + ((c & 63) >> 2);
            int koff = ((c >> 6) & 1) * 32 + (c & 3) * 8;
            gB[i] = WqT + (size_t)(n0 + row) * K + koff;
            lB[i] = Bs + c * 8;
        }

        f32x4 acc[4][4] = {};
        for (int k0 = 0; k0 < K; k0 += 64) {
            __syncthreads();
            #pragma unroll
            for (int i = 0; i < 8; i++) {
                float4 f = *(const float4*)(gA[i] + k0);
                uint2 p; p.x = pk2(f.x, f.y); p.y = pk2(f.z, f.w);
                *(uint2*)lA[i] = p;
            }
            #pragma unroll
            for (int i = 0; i < 4; i++) GLL16(gB[i] + k0, lB[i]);
            __syncthreads();
            #pragma unroll
            for (int ks = 0; ks < 2; ks++) {
                bfrag af[4], bf[4];
                #pragma unroll
                for (int i = 0; i < 4; i++)
                    af[i] = *(const bfrag*)(As + ((((wm >> 4) + i) * 2 + ks) * 64 + l16 * 4 + quad) * 8);
                #pragma unroll
                for (int i = 0; i < 4; i++)
                    bf[i] = *(const bfrag*)(Bs + ((((wn >> 4) + i) * 2 + ks) * 64 + l16 * 4 + quad) * 8);
                #pragma unroll
                for (int mi = 0; mi < 4; mi++)
                    #pragma unroll
                    for (int ni = 0; ni < 4; ni++)
                        acc[mi][ni] = __builtin_amdgcn_mfma_f32_16x16x32_bf16(af[mi], bf[ni], acc[mi][ni], 0, 0, 0);
            }
        }
        #pragma unroll
        for (int mi = 0; mi < 4; mi++)
            #pragma unroll
            for (int ni = 0; ni < 4; ni++) {
                int col = n0 + wn + ni * 16 + l16;
                #pragma unroll
                for (int r = 0; r < 4; r++) {
                    int row = m0 + wm + mi * 16 + quad * 4 + r;
                    Qp[(size_t)row * C_ + col] = f2bf(acc[mi][ni][r] * CS_);
                }
            }
        return;
    }

    // ---------------- kvproj path ----------------
    {
        short* As = lds;            // 32 x 64 bf16, frag order (2048)
        short* Bs = lds + 2048;     // 64 x 64 bf16, frag order (4096)
        int idx2 = bx - 512;
        int mode = idx2 >> 8;
        int m0 = (idx2 & 255) * 32;
        const float* A  = mode ? Vsrc : Ksrc;
        const short* Bt = mode ? WvT : WkT;
        short* Out      = mode ? Vfo : Kfo;

        int wrow = (w >> 1) * 16, wcol = (w & 1) * 32;

        int arow = tid >> 3, acol = (tid & 7) * 8;
        int akh = acol >> 5, aoct = (acol >> 3) & 3;
        short* asl = As + ((((arow >> 4) * 2 + akh) * 64 + (arow & 15) * 4 + aoct) * 8);
        const float* ag = A + (size_t)(m0 + arow) * C_ + acol;
        int brow = tid >> 2, bcol = (tid & 3) * 16;
        int bkh = bcol >> 5, boct = (bcol >> 3) & 3;
        short* bsl = Bs + ((((brow >> 4) * 2 + bkh) * 64 + (brow & 15) * 4 + boct) * 8);
        const short* bg = Bt + (size_t)brow * C_ + bcol;

        f32x4 acc[2] = {};
        for (int k0 = 0; k0 < C_; k0 += 64) {
            __syncthreads();
            {
                float4 fa = *(const float4*)(ag + k0);
                float4 fb = *(const float4*)(ag + k0 + 4);
                uint4 pa; pa.x = pk2(fa.x,fa.y); pa.y = pk2(fa.z,fa.w);
                          pa.z = pk2(fb.x,fb.y); pa.w = pk2(fb.z,fb.w);
                *(uint4*)asl = pa;
                uint4 t0 = *(const uint4*)(bg + k0);
                uint4 t1 = *(const uint4*)(bg + k0 + 8);
                *(uint4*)bsl = t0; *(uint4*)(bsl + 8) = t1;
            }
            __syncthreads();
            #pragma unroll
            for (int ks = 0; ks < 2; ks++) {
                bfrag af = *(const bfrag*)(As + (((wrow >> 4) * 2 + ks) * 64 + l16 * 4 + quad) * 8);
                #pragma unroll
                for (int ni = 0; ni < 2; ni++) {
                    int n = wcol + ni * 16;
                    bfrag bf = *(const bfrag*)(Bs + (((n >> 4) * 2 + ks) * 64 + l16 * 4 + quad) * 8);
                    acc[ni] = __builtin_amdgcn_mfma_f32_16x16x32_bf16(af, bf, acc[ni], 0, 0, 0);
                }
            }
        }
        if (mode == 0) {
            #pragma unroll
            for (int ni = 0; ni < 2; ni++)
                #pragma unroll
                for (int r = 0; r < 4; r++) {
                    int key = m0 + wrow + quad * 4 + r;
                    int d = wcol + ni * 16 + l16;
                    size_t adr = (size_t)(key >> 6) * 4096 +
                        ((((d >> 5) * 4 + ((key >> 4) & 3)) * 4 + ((d >> 3) & 3)) * 16 + (key & 15)) * 8 + (d & 7);
                    Out[adr] = f2bf(acc[ni][r]);
                }
        } else {
            #pragma unroll
            for (int ni = 0; ni < 2; ni++) {
                int ni2 = (w & 1) * 2 + ni;
                int key = m0 + wrow + quad * 4;
                int tile = key >> 6, kfk = (key >> 5) & 1, qv = (key >> 3) & 3;
                int jb = (quad & 1) * 4;
                uint2 pk; pk.x = pk2(acc[ni][0], acc[ni][1]); pk.y = pk2(acc[ni][2], acc[ni][3]);
                *(uint2*)(Out + (size_t)tile * 4096 + (((kfk * 4 + ni2) * 4 + qv) * 16 + l16) * 8 + jb) = pk;
            }
        }
    }
}

// ---------------- attention: 4 heads/block, K/V staged once, 16 waves ------
__global__ __launch_bounds__(1024, 4) void attn_kernel(
    const short* __restrict__ Qp, const short* __restrict__ Kfo,
    const short* __restrict__ Vfo, short* __restrict__ Out)
{
    // 96 KB: KV dbuf 2x8192 shorts @ [0,16384); Ps 16 waves x 2048 shorts
    __shared__ __align__(16) short lds[49152];
    int qb = blockIdx.x, hg = blockIdx.y, b = blockIdx.z;
    int tid = threadIdx.x, w = tid >> 6, lane = tid & 63;
    int quad = lane >> 4, l16 = lane & 15;
    int h = hg * 4 + (w >> 2);          // wave's head
    int wq = (w & 3) * 32;              // wave's q-row offset within 128
    short* Ps = lds + 16384 + w * 2048;
    int m0q = b * T_ + qb * 128;

    // qf straight from global: B-frag element e <-> consecutive d
    bfrag qf[2][2];
    #pragma unroll
    for (int nb = 0; nb < 2; nb++)
        #pragma unroll
        for (int kf = 0; kf < 2; kf++)
            qf[nb][kf] = *(const bfrag*)(Qp +
                (size_t)(m0q + wq + nb * 16 + l16) * C_ + h * 64 + kf * 32 + quad * 8);

    const short* Kb = Kfo + (size_t)b * (T_ * D_);
    const short* Vb = Vfo + (size_t)b * (T_ * D_);
    int q0 = qb * 128 + wq;

    f32x4 o[4][2] = {};
    float lsum[2] = {0.f, 0.f};
    int fragoff = (quad * 16 + l16) * 8;
    int st8 = tid * 8;                  // 1024 thr x 8 shorts = one K+V tile

    // prologue: stage tile 0 (threads 0..511 K, 512..1023 V)
    {
        const short* s0 = (tid < 512) ? Kb : (Vb - 4096);
        GLL16(s0 + st8, lds + st8);
    }
    __syncthreads();

    for (int t = 0; t < T_ / 64; t++) {
        short* bc = lds + (t & 1) * 8192;
        if (t + 1 < T_ / 64) {            // prefetch next tile into other buf
            short* bn = lds + ((t + 1) & 1) * 8192;
            const short* Kt = Kb + (t + 1) * 4096;
            const short* Vt = Vb + (t + 1) * 4096;
            const short* sn = (tid < 512) ? Kt : (Vt - 4096);
            GLL16(sn + st8, bn + st8);
        }
        bfrag ka[2][4];
        #pragma unroll
        for (int kf = 0; kf < 2; kf++)
            #pragma unroll
            for (int mi = 0; mi < 4; mi++)
                ka[kf][mi] = *(const bfrag*)(bc + (kf * 4 + mi) * 512 + fragoff);
        f32x4 s[4][2];
        #pragma unroll
        for (int mi = 0; mi < 4; mi++)
            #pragma unroll
            for (int nb = 0; nb < 2; nb++) {
                f32x4 z = {};
                z = __builtin_amdgcn_mfma_f32_16x16x32_bf16(ka[0][mi], qf[nb][0], z, 0, 0, 0);
                s[mi][nb] = __builtin_amdgcn_mfma_f32_16x16x32_bf16(ka[1][mi], qf[nb][1], z, 0, 0, 0);
            }
        bfrag va[2][4];
        #pragma unroll
        for (int kf = 0; kf < 2; kf++)
            #pragma unroll
            for (int mi = 0; mi < 4; mi++)
                va[kf][mi] = *(const bfrag*)(bc + 4096 + (kf * 4 + mi) * 512 + fragoff);
        #pragma unroll
        for (int nb = 0; nb < 2; nb++) {
            #pragma unroll
            for (int mi = 0; mi < 4; mi++) {
                float p0 = EXP2(s[mi][nb][0]);
                float p1 = EXP2(s[mi][nb][1]);
                float p2 = EXP2(s[mi][nb][2]);
                float p3 = EXP2(s[mi][nb][3]);
                lsum[nb] += (p0 + p1) + (p2 + p3);
                uint2 pk; pk.x = pk2(p0, p1); pk.y = pk2(p2, p3);
                int kf = mi >> 1, qp_ = (mi & 1) * 2 + (quad >> 1), jb = (quad & 1) * 4;
                *(uint2*)(Ps + (kf * 2 + nb) * 512 + qp_ * 128 + l16 * 8 + jb) = pk;
            }
        }
        #pragma unroll
        for (int nb = 0; nb < 2; nb++) {
            bfrag pf0 = *(const bfrag*)(Ps + (0 + nb) * 512 + quad * 128 + l16 * 8);
            bfrag pf1 = *(const bfrag*)(Ps + (2 + nb) * 512 + quad * 128 + l16 * 8);
            #pragma unroll
            for (int mi = 0; mi < 4; mi++) {
                o[mi][nb] = __builtin_amdgcn_mfma_f32_16x16x32_bf16(va[0][mi], pf0, o[mi][nb], 0, 0, 0);
                o[mi][nb] = __builtin_amdgcn_mfma_f32_16x16x32_bf16(va[1][mi], pf1, o[mi][nb], 0, 0, 0);
            }
        }
        __syncthreads();   // prefetch landed; all waves done with bc
    }
    #pragma unroll
    for (int nb = 0; nb < 2; nb++) {
        float l = lsum[nb];
        l += __shfl_xor(l, 16, 64);
        l += __shfl_xor(l, 32, 64);
        float rl = 1.0f / l;
        size_t row = (size_t)(b * T_ + q0 + nb * 16 + l16);
        #pragma unroll
        for (int mi = 0; mi < 4; mi++) {
            uint2 pk; pk.x = pk2(o[mi][nb][0] * rl, o[mi][nb][1] * rl);
                      pk.y = pk2(o[mi][nb][2] * rl, o[mi][nb][3] * rl);
            *(uint2*)(Out + row * C_ + h * 64 + mi * 16 + quad * 4) = pk;
        }
    }
}

// ---------------- final GEMM, 128x128 tile, BK=64 (m97 structure) ----------
__global__ __launch_bounds__(256) void gemm_fin_kernel(
    const short* __restrict__ A, const short* __restrict__ Bt,
    const float* __restrict__ bias, float* __restrict__ Out)
{
    __shared__ __align__(16) short As[8192];   // 128 x 64, frag order
    __shared__ __align__(16) short Bs[8192];   // 128 x 64, frag order
    const int N = C_, K = C_;
    int tid = threadIdx.x, w = tid >> 6, lane = tid & 63;
    int quad = lane >> 4, l16 = lane & 15;
    int wm = (w >> 1) * 64, wn = (w & 1) * 64;
    int m0 = blockIdx.y * 128, n0 = blockIdx.x * 128;

    const short* gA[4]; short* lA[4];
    const short* gB[4]; short* lB[4];
    #pragma unroll
    for (int i = 0; i < 4; i++) {
        int c = tid + 256 * i;
        int row = ((c >> 7) << 4) + ((c & 63) >> 2);
        int koff = ((c >> 6) & 1) * 32 + (c & 3) * 8;
        gA[i] = A + (size_t)(m0 + row) * K + koff;
        lA[i] = As + c * 8;
        gB[i] = Bt + (size_t)(n0 + row) * K + koff;
        lB[i] = Bs + c * 8;
    }

    f32x4 acc[4][4] = {};
    for (int k0 = 0; k0 < K; k0 += 64) {
        __syncthreads();
        #pragma unroll
        for (int i = 0; i < 4; i++) GLL16(gA[i] + k0, lA[i]);
        #pragma unroll
        for (int i = 0; i < 4; i++) GLL16(gB[i] + k0, lB[i]);
        __syncthreads();
        #pragma unroll
        for (int ks = 0; ks < 2; ks++) {
            bfrag af[4], bf[4];
            #pragma unroll
            for (int i = 0; i < 4; i++)
                af[i] = *(const bfrag*)(As + ((((wm >> 4) + i) * 2 + ks) * 64 + l16 * 4 + quad) * 8);
            #pragma unroll
            for (int i = 0; i < 4; i++)
                bf[i] = *(const bfrag*)(Bs + ((((wn >> 4) + i) * 2 + ks) * 64 + l16 * 4 + quad) * 8);
            #pragma unroll
            for (int mi = 0; mi < 4; mi++)
                #pragma unroll
                for (int ni = 0; ni < 4; ni++)
                    acc[mi][ni] = __builtin_amdgcn_mfma_f32_16x16x32_bf16(af[mi], bf[ni], acc[mi][ni], 0, 0, 0);
        }
    }
    #pragma unroll
    for (int mi = 0; mi < 4; mi++)
        #pragma unroll
        for (int ni = 0; ni < 4; ni++) {
            int col = n0 + wn + ni * 16 + l16;
            float bv = bias[col];
            #pragma unroll
            for (int r = 0; r < 4; r++) {
                int row = m0 + wm + mi * 16 + quad * 4 + r;
                Out[(size_t)row * N + col] = acc[mi][ni][r] + bv;
            }
        }
}

extern "C" void kernel_launch(void* const* d_in, const int* in_sizes, int n_in,
                              void* d_out, int out_size, void* d_ws, size_t ws_size,
                              hipStream_t stream) {
    const float* q  = (const float*)d_in[0];
    const float* k  = (const float*)d_in[1];
    const float* v  = (const float*)d_in[2];
    const float* Wq = (const float*)d_in[3];
    const float* Wk = (const float*)d_in[4];
    const float* Wv = (const float*)d_in[5];
    const float* Wp = (const float*)d_in[6];
    const float* bp = (const float*)d_in[7];
    float* out = (float*)d_out;

    char* ws = (char*)d_ws;
    short* Qp       = (short*)(ws);                   // 16 MB [BT][C] bf16, pre-scaled
    short* attn_out = (short*)(ws + (16u << 20));     // 16 MB [BT][C]
    short* WqT  = (short*)(ws + (32u << 20));         //  2 MB
    short* WpT  = (short*)(ws + (34u << 20));         //  2 MB
    short* Kfo  = (short*)(ws + (36u << 20));         //  1 MB
    short* Vfo  = (short*)(ws + (37u << 20));         //  1 MB
    short* WkT  = (short*)(ws + (38u << 20));         // 128 KB
    short* WvT  = (short*)(ws + (38u << 20) + (1u << 18));

    dim3 blk(256);
    prep_kernel<<<544, blk, 0, stream>>>(Wq, Wk, Wv, Wp, WqT, WkT, WvT, WpT);
    proj_kernel<<<1024, blk, 0, stream>>>(q, k, v, WqT, WkT, WvT, Qp, Kfo, Vfo);
    attn_kernel<<<dim3(16, 4, 4), dim3(1024), 0, stream>>>(Qp, Kfo, Vfo, attn_out);
    gemm_fin_kernel<<<dim3(8, 64), blk, 0, stream>>>(attn_out, WpT, bp, out);
}

// Round 9
// 277.470 us; speedup vs baseline: 1.0624x; 1.0624x over previous
//
#include <hip/hip_runtime.h>
#include <hip/hip_bf16.h>

// MQA B=4 T=2048 C=1024 H=16 D=64.
// R14: XCD-locality round. R13 counters exposed proj_kernel: 89us, FETCH
// 166MB vs ~100MB ideal, MfmaUtil 8% -> HBM over-fetch. Cause: the 8 blocks
// sharing one A-slice are CONSECUTIVE bx -> round-robined across 8 XCDs ->
// each XCD's L2 re-fetches the slice. Fix (T1): remap qproj m0=(bx&63),
// n0=(bx>>6) so same-A blocks have equal bx%8 (same XCD); same for gemm_fin
// (grid swapped to (64,8), m on x). Index remap only; math unchanged.
// attn (R13 4-head/block structure, ~60-70us) unchanged.

#define B_ 4
#define T_ 2048
#define C_ 1024
#define H_ 16
#define D_ 64
#define BT_ (B_*T_)
#define CS_ 0.1803368801111204f   // (1/sqrt(64)) * log2(e)

typedef short bfrag __attribute__((ext_vector_type(8)));   // 8 bf16
typedef float f32x4 __attribute__((ext_vector_type(4)));
typedef __bf16 bf2_t __attribute__((ext_vector_type(2)));

// Native casts: clang lowers f32->bf16 on gfx950 to v_cvt_pk_bf16_f32 (RNE).
static __device__ inline short f2bf(float f){
    union { __bf16 h; short s; } c; c.h = (__bf16)f;
    return c.s;
}
static __device__ inline unsigned pk2(float a, float b){
    union { bf2_t v; unsigned u; } c;
    c.v[0] = (__bf16)a; c.v[1] = (__bf16)b;
    return c.u;
}

#if __has_builtin(__builtin_amdgcn_global_load_lds)
#define GLL16(g,l) __builtin_amdgcn_global_load_lds(                              \
    (const __attribute__((address_space(1))) void*)(g),                           \
    (__attribute__((address_space(3))) void*)(l), 16, 0, 0)
#else
#define GLL16(g,l) (*(uint4*)(l) = *(const uint4*)(g))
#endif

#if __has_builtin(__builtin_amdgcn_exp2f)
#define EXP2(x) __builtin_amdgcn_exp2f(x)
#else
#define EXP2(x) __expf((x)*0.693147180559945f)
#endif

// ---------------- prep: weight transposes only ----------------------------
__global__ __launch_bounds__(256) void prep_kernel(
    const float* __restrict__ Wq, const float* __restrict__ Wk,
    const float* __restrict__ Wv, const float* __restrict__ Wp,
    short* __restrict__ WqT, short* __restrict__ WkT,
    short* __restrict__ WvT, short* __restrict__ WpT)
{
    int b2 = blockIdx.x, tid = threadIdx.x;
    __shared__ short Ls[64][65];
    const float* W; short* Wt; int N, idx;
    if (b2 < 256)      { W = Wq; Wt = WqT; N = 1024; idx = b2; }
    else if (b2 < 272) { W = Wk; Wt = WkT; N = 64;   idx = b2 - 256; }
    else if (b2 < 288) { W = Wv; Wt = WvT; N = 64;   idx = b2 - 272; }
    else               { W = Wp; Wt = WpT; N = 1024; idx = b2 - 288; }
    int nx = N >> 6;
    int n0 = (idx % nx) * 64, k0 = (idx / nx) * 64;
    {
        int kr = tid >> 2, c4 = (tid & 3) * 16;
        const float* g = W + (size_t)(k0 + kr) * N + n0 + c4;
        #pragma unroll
        for (int e = 0; e < 16; e++) Ls[kr][c4 + e] = f2bf(g[e]);
    }
    __syncthreads();
    {
        int nr = tid >> 2, kc = (tid & 3) * 16;
        __align__(16) short tmp[16];
        #pragma unroll
        for (int e = 0; e < 16; e++) tmp[e] = Ls[kc + e][nr];
        short* o = Wt + (size_t)(n0 + nr) * 1024 + k0 + kc;
        *(uint4*)(o)     = *(uint4*)tmp;
        *(uint4*)(o + 8) = *(uint4*)(tmp + 8);
    }
}

// ---------------- merged projections: blocks 0..511 qproj, 512..1023 kv ----
__global__ __launch_bounds__(256) void proj_kernel(
    const float* __restrict__ Aq, const float* __restrict__ Ksrc,
    const float* __restrict__ Vsrc,
    const short* __restrict__ WqT, const short* __restrict__ WkT,
    const short* __restrict__ WvT,
    short* __restrict__ Qp, short* __restrict__ Kfo, short* __restrict__ Vfo)
{
    __shared__ __align__(16) short lds[16384];   // 32 KB shared by both paths
    int bx = blockIdx.x, tid = threadIdx.x;
    int w = tid >> 6, lane = tid & 63;
    int quad = lane >> 4, l16 = lane & 15;

    if (bx < 512) {
        // ---------------- qproj path ----------------
        // XCD-locality: blocks sharing an A-slice (same m0) are spaced 64
        // apart -> identical bx%8 -> same XCD L2 caches the slice once.
        short* As = lds;            // 128 x 64, frag order
        short* Bs = lds + 8192;     // 128 x 64, frag order
        const int K = C_;
        int wm = (w >> 1) * 64, wn = (w & 1) * 64;
        int m0 = (bx & 63) * 128, n0 = (bx >> 6) * 128;

        const float* gA[8]; short* lA[8];
        #pragma unroll
        for (int i = 0; i < 8; i++) {
            int c = tid + 256 * i;            // float4-chunk id, 0..2047
            int row = c >> 4, fc = c & 15;    // 16 float4 per 64-col row
            gA[i] = Aq + (size_t)(m0 + row) * K + fc * 4;
            int m16 = row >> 4, l16r = row & 15;
            int ks = fc >> 3, q4 = (fc >> 1) & 3, e0 = (fc & 1) * 4;
            lA[i] = As + ((m16 * 2 + ks) * 64 + l16r * 4 + q4) * 8 + e0;
        }
        const short* gB[4]; short* lB[4];
        #pragma unroll
        for (int i = 0; i < 4; i++) {
            int c = tid + 256 * i;
            int row = ((c >> 7) << 4) + ((c & 63) >> 2);
            int koff = ((c >> 6) & 1) * 32 + (c & 3) * 8;
            gB[i] = WqT + (size_t)(n0 + row) * K + koff;
            lB[i] = Bs + c * 8;
        }

        f32x4 acc[4][4] = {};
        for (int k0 = 0; k0 < K; k0 += 64) {
            __syncthreads();
            #pragma unroll
            for (int i = 0; i < 8; i++) {
                float4 f = *(const float4*)(gA[i] + k0);
                uint2 p; p.x = pk2(f.x, f.y); p.y = pk2(f.z, f.w);
                *(uint2*)lA[i] = p;
            }
            #pragma unroll
            for (int i = 0; i < 4; i++) GLL16(gB[i] + k0, lB[i]);
            __syncthreads();
            #pragma unroll
            for (int ks = 0; ks < 2; ks++) {
                bfrag af[4], bf[4];
                #pragma unroll
                for (int i = 0; i < 4; i++)
                    af[i] = *(const bfrag*)(As + ((((wm >> 4) + i) * 2 + ks) * 64 + l16 * 4 + quad) * 8);
                #pragma unroll
                for (int i = 0; i < 4; i++)
                    bf[i] = *(const bfrag*)(Bs + ((((wn >> 4) + i) * 2 + ks) * 64 + l16 * 4 + quad) * 8);
                #pragma unroll
                for (int mi = 0; mi < 4; mi++)
                    #pragma unroll
                    for (int ni = 0; ni < 4; ni++)
                        acc[mi][ni] = __builtin_amdgcn_mfma_f32_16x16x32_bf16(af[mi], bf[ni], acc[mi][ni], 0, 0, 0);
            }
        }
        #pragma unroll
        for (int mi = 0; mi < 4; mi++)
            #pragma unroll
            for (int ni = 0; ni < 4; ni++) {
                int col = n0 + wn + ni * 16 + l16;
                #pragma unroll
                for (int r = 0; r < 4; r++) {
                    int row = m0 + wm + mi * 16 + quad * 4 + r;
                    Qp[(size_t)row * C_ + col] = f2bf(acc[mi][ni][r] * CS_);
                }
            }
        return;
    }

    // ---------------- kvproj path ----------------
    {
        short* As = lds;            // 32 x 64 bf16, frag order (2048)
        short* Bs = lds + 2048;     // 64 x 64 bf16, frag order (4096)
        int idx2 = bx - 512;
        int mode = idx2 >> 8;
        int m0 = (idx2 & 255) * 32;
        const float* A  = mode ? Vsrc : Ksrc;
        const short* Bt = mode ? WvT : WkT;
        short* Out      = mode ? Vfo : Kfo;

        int wrow = (w >> 1) * 16, wcol = (w & 1) * 32;

        int arow = tid >> 3, acol = (tid & 7) * 8;
        int akh = acol >> 5, aoct = (acol >> 3) & 3;
        short* asl = As + ((((arow >> 4) * 2 + akh) * 64 + (arow & 15) * 4 + aoct) * 8);
        const float* ag = A + (size_t)(m0 + arow) * C_ + acol;
        int brow = tid >> 2, bcol = (tid & 3) * 16;
        int bkh = bcol >> 5, boct = (bcol >> 3) & 3;
        short* bsl = Bs + ((((brow >> 4) * 2 + bkh) * 64 + (brow & 15) * 4 + boct) * 8);
        const short* bg = Bt + (size_t)brow * C_ + bcol;

        f32x4 acc[2] = {};
        for (int k0 = 0; k0 < C_; k0 += 64) {
            __syncthreads();
            {
                float4 fa = *(const float4*)(ag + k0);
                float4 fb = *(const float4*)(ag + k0 + 4);
                uint4 pa; pa.x = pk2(fa.x,fa.y); pa.y = pk2(fa.z,fa.w);
                          pa.z = pk2(fb.x,fb.y); pa.w = pk2(fb.z,fb.w);
                *(uint4*)asl = pa;
                uint4 t0 = *(const uint4*)(bg + k0);
                uint4 t1 = *(const uint4*)(bg + k0 + 8);
                *(uint4*)bsl = t0; *(uint4*)(bsl + 8) = t1;
            }
            __syncthreads();
            #pragma unroll
            for (int ks = 0; ks < 2; ks++) {
                bfrag af = *(const bfrag*)(As + (((wrow >> 4) * 2 + ks) * 64 + l16 * 4 + quad) * 8);
                #pragma unroll
                for (int ni = 0; ni < 2; ni++) {
                    int n = wcol + ni * 16;
                    bfrag bf = *(const bfrag*)(Bs + (((n >> 4) * 2 + ks) * 64 + l16 * 4 + quad) * 8);
                    acc[ni] = __builtin_amdgcn_mfma_f32_16x16x32_bf16(af, bf, acc[ni], 0, 0, 0);
                }
            }
        }
        if (mode == 0) {
            #pragma unroll
            for (int ni = 0; ni < 2; ni++)
                #pragma unroll
                for (int r = 0; r < 4; r++) {
                    int key = m0 + wrow + quad * 4 + r;
                    int d = wcol + ni * 16 + l16;
                    size_t adr = (size_t)(key >> 6) * 4096 +
                        ((((d >> 5) * 4 + ((key >> 4) & 3)) * 4 + ((d >> 3) & 3)) * 16 + (key & 15)) * 8 + (d & 7);
                    Out[adr] = f2bf(acc[ni][r]);
                }
        } else {
            #pragma unroll
            for (int ni = 0; ni < 2; ni++) {
                int ni2 = (w & 1) * 2 + ni;
                int key = m0 + wrow + quad * 4;
                int tile = key >> 6, kfk = (key >> 5) & 1, qv = (key >> 3) & 3;
                int jb = (quad & 1) * 4;
                uint2 pk; pk.x = pk2(acc[ni][0], acc[ni][1]); pk.y = pk2(acc[ni][2], acc[ni][3]);
                *(uint2*)(Out + (size_t)tile * 4096 + (((kfk * 4 + ni2) * 4 + qv) * 16 + l16) * 8 + jb) = pk;
            }
        }
    }
}

// ---------------- attention: 4 heads/block, K/V staged once, 16 waves ------
__global__ __launch_bounds__(1024, 4) void attn_kernel(
    const short* __restrict__ Qp, const short* __restrict__ Kfo,
    const short* __restrict__ Vfo, short* __restrict__ Out)
{
    // 96 KB: KV dbuf 2x8192 shorts @ [0,16384); Ps 16 waves x 2048 shorts
    __shared__ __align__(16) short lds[49152];
    int qb = blockIdx.x, hg = blockIdx.y, b = blockIdx.z;
    int tid = threadIdx.x, w = tid >> 6, lane = tid & 63;
    int quad = lane >> 4, l16 = lane & 15;
    int h = hg * 4 + (w >> 2);          // wave's head
    int wq = (w & 3) * 32;              // wave's q-row offset within 128
    short* Ps = lds + 16384 + w * 2048;
    int m0q = b * T_ + qb * 128;

    // qf straight from global: B-frag element e <-> consecutive d
    bfrag qf[2][2];
    #pragma unroll
    for (int nb = 0; nb < 2; nb++)
        #pragma unroll
        for (int kf = 0; kf < 2; kf++)
            qf[nb][kf] = *(const bfrag*)(Qp +
                (size_t)(m0q + wq + nb * 16 + l16) * C_ + h * 64 + kf * 32 + quad * 8);

    const short* Kb = Kfo + (size_t)b * (T_ * D_);
    const short* Vb = Vfo + (size_t)b * (T_ * D_);
    int q0 = qb * 128 + wq;

    f32x4 o[4][2] = {};
    float lsum[2] = {0.f, 0.f};
    int fragoff = (quad * 16 + l16) * 8;
    int st8 = tid * 8;                  // 1024 thr x 8 shorts = one K+V tile

    // prologue: stage tile 0 (threads 0..511 K, 512..1023 V)
    {
        const short* s0 = (tid < 512) ? Kb : (Vb - 4096);
        GLL16(s0 + st8, lds + st8);
    }
    __syncthreads();

    for (int t = 0; t < T_ / 64; t++) {
        short* bc = lds + (t & 1) * 8192;
        if (t + 1 < T_ / 64) {            // prefetch next tile into other buf
            short* bn = lds + ((t + 1) & 1) * 8192;
            const short* Kt = Kb + (t + 1) * 4096;
            const short* Vt = Vb + (t + 1) * 4096;
            const short* sn = (tid < 512) ? Kt : (Vt - 4096);
            GLL16(sn + st8, bn + st8);
        }
        bfrag ka[2][4];
        #pragma unroll
        for (int kf = 0; kf < 2; kf++)
            #pragma unroll
            for (int mi = 0; mi < 4; mi++)
                ka[kf][mi] = *(const bfrag*)(bc + (kf * 4 + mi) * 512 + fragoff);
        f32x4 s[4][2];
        #pragma unroll
        for (int mi = 0; mi < 4; mi++)
            #pragma unroll
            for (int nb = 0; nb < 2; nb++) {
                f32x4 z = {};
                z = __builtin_amdgcn_mfma_f32_16x16x32_bf16(ka[0][mi], qf[nb][0], z, 0, 0, 0);
                s[mi][nb] = __builtin_amdgcn_mfma_f32_16x16x32_bf16(ka[1][mi], qf[nb][1], z, 0, 0, 0);
            }
        bfrag va[2][4];
        #pragma unroll
        for (int kf = 0; kf < 2; kf++)
            #pragma unroll
            for (int mi = 0; mi < 4; mi++)
                va[kf][mi] = *(const bfrag*)(bc + 4096 + (kf * 4 + mi) * 512 + fragoff);
        #pragma unroll
        for (int nb = 0; nb < 2; nb++) {
            #pragma unroll
            for (int mi = 0; mi < 4; mi++) {
                float p0 = EXP2(s[mi][nb][0]);
                float p1 = EXP2(s[mi][nb][1]);
                float p2 = EXP2(s[mi][nb][2]);
                float p3 = EXP2(s[mi][nb][3]);
                lsum[nb] += (p0 + p1) + (p2 + p3);
                uint2 pk; pk.x = pk2(p0, p1); pk.y = pk2(p2, p3);
                int kf = mi >> 1, qp_ = (mi & 1) * 2 + (quad >> 1), jb = (quad & 1) * 4;
                *(uint2*)(Ps + (kf * 2 + nb) * 512 + qp_ * 128 + l16 * 8 + jb) = pk;
            }
        }
        #pragma unroll
        for (int nb = 0; nb < 2; nb++) {
            bfrag pf0 = *(const bfrag*)(Ps + (0 + nb) * 512 + quad * 128 + l16 * 8);
            bfrag pf1 = *(const bfrag*)(Ps + (2 + nb) * 512 + quad * 128 + l16 * 8);
            #pragma unroll
            for (int mi = 0; mi < 4; mi++) {
                o[mi][nb] = __builtin_amdgcn_mfma_f32_16x16x32_bf16(va[0][mi], pf0, o[mi][nb], 0, 0, 0);
                o[mi][nb] = __builtin_amdgcn_mfma_f32_16x16x32_bf16(va[1][mi], pf1, o[mi][nb], 0, 0, 0);
            }
        }
        __syncthreads();   // prefetch landed; all waves done with bc
    }
    #pragma unroll
    for (int nb = 0; nb < 2; nb++) {
        float l = lsum[nb];
        l += __shfl_xor(l, 16, 64);
        l += __shfl_xor(l, 32, 64);
        float rl = 1.0f / l;
        size_t row = (size_t)(b * T_ + q0 + nb * 16 + l16);
        #pragma unroll
        for (int mi = 0; mi < 4; mi++) {
            uint2 pk; pk.x = pk2(o[mi][nb][0] * rl, o[mi][nb][1] * rl);
                      pk.y = pk2(o[mi][nb][2] * rl, o[mi][nb][3] * rl);
            *(uint2*)(Out + row * C_ + h * 64 + mi * 16 + quad * 4) = pk;
        }
    }
}

// ---------------- final GEMM, 128x128 tile, BK=64, m on grid.x (XCD) -------
__global__ __launch_bounds__(256) void gemm_fin_kernel(
    const short* __restrict__ A, const short* __restrict__ Bt,
    const float* __restrict__ bias, float* __restrict__ Out)
{
    __shared__ __align__(16) short As[8192];   // 128 x 64, frag order
    __shared__ __align__(16) short Bs[8192];   // 128 x 64, frag order
    const int N = C_, K = C_;
    int tid = threadIdx.x, w = tid >> 6, lane = tid & 63;
    int quad = lane >> 4, l16 = lane & 15;
    int wm = (w >> 1) * 64, wn = (w & 1) * 64;
    // XCD-locality: same-A blocks (same m0) spaced 64 apart -> same XCD.
    int m0 = blockIdx.x * 128, n0 = blockIdx.y * 128;

    const short* gA[4]; short* lA[4];
    const short* gB[4]; short* lB[4];
    #pragma unroll
    for (int i = 0; i < 4; i++) {
        int c = tid + 256 * i;
        int row = ((c >> 7) << 4) + ((c & 63) >> 2);
        int koff = ((c >> 6) & 1) * 32 + (c & 3) * 8;
        gA[i] = A + (size_t)(m0 + row) * K + koff;
        lA[i] = As + c * 8;
        gB[i] = Bt + (size_t)(n0 + row) * K + koff;
        lB[i] = Bs + c * 8;
    }

    f32x4 acc[4][4] = {};
    for (int k0 = 0; k0 < K; k0 += 64) {
        __syncthreads();
        #pragma unroll
        for (int i = 0; i < 4; i++) GLL16(gA[i] + k0, lA[i]);
        #pragma unroll
        for (int i = 0; i < 4; i++) GLL16(gB[i] + k0, lB[i]);
        __syncthreads();
        #pragma unroll
        for (int ks = 0; ks < 2; ks++) {
            bfrag af[4], bf[4];
            #pragma unroll
            for (int i = 0; i < 4; i++)
                af[i] = *(const bfrag*)(As + ((((wm >> 4) + i) * 2 + ks) * 64 + l16 * 4 + quad) * 8);
            #pragma unroll
            for (int i = 0; i < 4; i++)
                bf[i] = *(const bfrag*)(Bs + ((((wn >> 4) + i) * 2 + ks) * 64 + l16 * 4 + quad) * 8);
            #pragma unroll
            for (int mi = 0; mi < 4; mi++)
                #pragma unroll
                for (int ni = 0; ni < 4; ni++)
                    acc[mi][ni] = __builtin_amdgcn_mfma_f32_16x16x32_bf16(af[mi], bf[ni], acc[mi][ni], 0, 0, 0);
        }
    }
    #pragma unroll
    for (int mi = 0; mi < 4; mi++)
        #pragma unroll
        for (int ni = 0; ni < 4; ni++) {
            int col = n0 + wn + ni * 16 + l16;
            float bv = bias[col];
            #pragma unroll
            for (int r = 0; r < 4; r++) {
                int row = m0 + wm + mi * 16 + quad * 4 + r;
                Out[(size_t)row * N + col] = acc[mi][ni][r] + bv;
            }
        }
}

extern "C" void kernel_launch(void* const* d_in, const int* in_sizes, int n_in,
                              void* d_out, int out_size, void* d_ws, size_t ws_size,
                              hipStream_t stream) {
    const float* q  = (const float*)d_in[0];
    const float* k  = (const float*)d_in[1];
    const float* v  = (const float*)d_in[2];
    const float* Wq = (const float*)d_in[3];
    const float* Wk = (const float*)d_in[4];
    const float* Wv = (const float*)d_in[5];
    const float* Wp = (const float*)d_in[6];
    const float* bp = (const float*)d_in[7];
    float* out = (float*)d_out;

    char* ws = (char*)d_ws;
    short* Qp       = (short*)(ws);                   // 16 MB [BT][C] bf16, pre-scaled
    short* attn_out = (short*)(ws + (16u << 20));     // 16 MB [BT][C]
    short* WqT  = (short*)(ws + (32u << 20));         //  2 MB
    short* WpT  = (short*)(ws + (34u << 20));         //  2 MB
    short* Kfo  = (short*)(ws + (36u << 20));         //  1 MB
    short* Vfo  = (short*)(ws + (37u << 20));         //  1 MB
    short* WkT  = (short*)(ws + (38u << 20));         // 128 KB
    short* WvT  = (short*)(ws + (38u << 20) + (1u << 18));

    dim3 blk(256);
    prep_kernel<<<544, blk, 0, stream>>>(Wq, Wk, Wv, Wp, WqT, WkT, WvT, WpT);
    proj_kernel<<<1024, blk, 0, stream>>>(q, k, v, WqT, WkT, WvT, Qp, Kfo, Vfo);
    attn_kernel<<<dim3(16, 4, 4), dim3(1024), 0, stream>>>(Qp, Kfo, Vfo, attn_out);
    gemm_fin_kernel<<<dim3(64, 8), blk, 0, stream>>>(attn_out, WpT, bp, out);
}

// Round 10
// 266.200 us; speedup vs baseline: 1.1074x; 1.0423x over previous
//
#include <hip/hip_runtime.h>
#include <hip/hip_bf16.h>

// MQA B=4 T=2048 C=1024 H=16 D=64.
// R15: overlap round. attn split 16-wave/4-head -> 8-wave/2-head blocks,
// grid (16,8,4)=512 = exactly 2 blocks/CU (64KB LDS): two independent
// barrier domains hide each other's drains. lsum now via MFMA ones-trick
// (lacc = mfma(ones,pf,lacc): every C row = column-sum of P) -> deletes
// 32 VALU adds/iter + epilogue shfl reduce; denominator sums bf16 P,
// consistent with bf16 numerator. proj: A-loads for step k+1 issued right
// after the GLLs (piggyback on the barrier's vmcnt drain) -> next pack has
// zero load wait. gemm_fin/prep unchanged (R14 XCD mapping kept).

#define B_ 4
#define T_ 2048
#define C_ 1024
#define H_ 16
#define D_ 64
#define BT_ (B_*T_)
#define CS_ 0.1803368801111204f   // (1/sqrt(64)) * log2(e)

typedef short bfrag __attribute__((ext_vector_type(8)));   // 8 bf16
typedef float f32x4 __attribute__((ext_vector_type(4)));
typedef __bf16 bf2_t __attribute__((ext_vector_type(2)));

// Native casts: clang lowers f32->bf16 on gfx950 to v_cvt_pk_bf16_f32 (RNE).
static __device__ inline short f2bf(float f){
    union { __bf16 h; short s; } c; c.h = (__bf16)f;
    return c.s;
}
static __device__ inline unsigned pk2(float a, float b){
    union { bf2_t v; unsigned u; } c;
    c.v[0] = (__bf16)a; c.v[1] = (__bf16)b;
    return c.u;
}

#if __has_builtin(__builtin_amdgcn_global_load_lds)
#define GLL16(g,l) __builtin_amdgcn_global_load_lds(                              \
    (const __attribute__((address_space(1))) void*)(g),                           \
    (__attribute__((address_space(3))) void*)(l), 16, 0, 0)
#else
#define GLL16(g,l) (*(uint4*)(l) = *(const uint4*)(g))
#endif

#if __has_builtin(__builtin_amdgcn_exp2f)
#define EXP2(x) __builtin_amdgcn_exp2f(x)
#else
#define EXP2(x) __expf((x)*0.693147180559945f)
#endif

// ---------------- prep: weight transposes only ----------------------------
__global__ __launch_bounds__(256) void prep_kernel(
    const float* __restrict__ Wq, const float* __restrict__ Wk,
    const float* __restrict__ Wv, const float* __restrict__ Wp,
    short* __restrict__ WqT, short* __restrict__ WkT,
    short* __restrict__ WvT, short* __restrict__ WpT)
{
    int b2 = blockIdx.x, tid = threadIdx.x;
    __shared__ short Ls[64][65];
    const float* W; short* Wt; int N, idx;
    if (b2 < 256)      { W = Wq; Wt = WqT; N = 1024; idx = b2; }
    else if (b2 < 272) { W = Wk; Wt = WkT; N = 64;   idx = b2 - 256; }
    else if (b2 < 288) { W = Wv; Wt = WvT; N = 64;   idx = b2 - 272; }
    else               { W = Wp; Wt = WpT; N = 1024; idx = b2 - 288; }
    int nx = N >> 6;
    int n0 = (idx % nx) * 64, k0 = (idx / nx) * 64;
    {
        int kr = tid >> 2, c4 = (tid & 3) * 16;
        const float* g = W + (size_t)(k0 + kr) * N + n0 + c4;
        #pragma unroll
        for (int e = 0; e < 16; e++) Ls[kr][c4 + e] = f2bf(g[e]);
    }
    __syncthreads();
    {
        int nr = tid >> 2, kc = (tid & 3) * 16;
        __align__(16) short tmp[16];
        #pragma unroll
        for (int e = 0; e < 16; e++) tmp[e] = Ls[kc + e][nr];
        short* o = Wt + (size_t)(n0 + nr) * 1024 + k0 + kc;
        *(uint4*)(o)     = *(uint4*)tmp;
        *(uint4*)(o + 8) = *(uint4*)(tmp + 8);
    }
}

// ---------------- merged projections: blocks 0..511 qproj, 512..1023 kv ----
__global__ __launch_bounds__(256) void proj_kernel(
    const float* __restrict__ Aq, const float* __restrict__ Ksrc,
    const float* __restrict__ Vsrc,
    const short* __restrict__ WqT, const short* __restrict__ WkT,
    const short* __restrict__ WvT,
    short* __restrict__ Qp, short* __restrict__ Kfo, short* __restrict__ Vfo)
{
    __shared__ __align__(16) short lds[16384];   // 32 KB shared by both paths
    int bx = blockIdx.x, tid = threadIdx.x;
    int w = tid >> 6, lane = tid & 63;
    int quad = lane >> 4, l16 = lane & 15;

    if (bx < 512) {
        // ---------------- qproj path ----------------
        // XCD-locality: same-A blocks spaced 64 apart -> same bx%8 -> same XCD.
        short* As = lds;            // 128 x 64, frag order
        short* Bs = lds + 8192;     // 128 x 64, frag order
        const int K = C_;
        int wm = (w >> 1) * 64, wn = (w & 1) * 64;
        int m0 = (bx & 63) * 128, n0 = (bx >> 6) * 128;

        const float* gA[8]; short* lA[8];
        #pragma unroll
        for (int i = 0; i < 8; i++) {
            int c = tid + 256 * i;            // float4-chunk id, 0..2047
            int row = c >> 4, fc = c & 15;    // 16 float4 per 64-col row
            gA[i] = Aq + (size_t)(m0 + row) * K + fc * 4;
            int m16 = row >> 4, l16r = row & 15;
            int ks = fc >> 3, q4 = (fc >> 1) & 3, e0 = (fc & 1) * 4;
            lA[i] = As + ((m16 * 2 + ks) * 64 + l16r * 4 + q4) * 8 + e0;
        }
        const short* gB[4]; short* lB[4];
        #pragma unroll
        for (int i = 0; i < 4; i++) {
            int c = tid + 256 * i;
            int row = ((c >> 7) << 4) + ((c & 63) >> 2);
            int koff = ((c >> 6) & 1) * 32 + (c & 3) * 8;
            gB[i] = WqT + (size_t)(n0 + row) * K + koff;
            lB[i] = Bs + c * 8;
        }

        // preload A for k0=0; reloads issued early each iter (piggyback on
        // the barrier's vmcnt drain -> next pack has zero load wait)
        float4 fA[8];
        #pragma unroll
        for (int i = 0; i < 8; i++) fA[i] = *(const float4*)(gA[i]);

        f32x4 acc[4][4] = {};
        for (int k0 = 0; k0 < K; k0 += 64) {
            __syncthreads();
            #pragma unroll
            for (int i = 0; i < 8; i++) {
                uint2 p; p.x = pk2(fA[i].x, fA[i].y); p.y = pk2(fA[i].z, fA[i].w);
                *(uint2*)lA[i] = p;
            }
            #pragma unroll
            for (int i = 0; i < 4; i++) GLL16(gB[i] + k0, lB[i]);
            if (k0 + 64 < K) {
                #pragma unroll
                for (int i = 0; i < 8; i++) fA[i] = *(const float4*)(gA[i] + k0 + 64);
            }
            __syncthreads();
            #pragma unroll
            for (int ks = 0; ks < 2; ks++) {
                bfrag af[4], bf[4];
                #pragma unroll
                for (int i = 0; i < 4; i++)
                    af[i] = *(const bfrag*)(As + ((((wm >> 4) + i) * 2 + ks) * 64 + l16 * 4 + quad) * 8);
                #pragma unroll
                for (int i = 0; i < 4; i++)
                    bf[i] = *(const bfrag*)(Bs + ((((wn >> 4) + i) * 2 + ks) * 64 + l16 * 4 + quad) * 8);
                #pragma unroll
                for (int mi = 0; mi < 4; mi++)
                    #pragma unroll
                    for (int ni = 0; ni < 4; ni++)
                        acc[mi][ni] = __builtin_amdgcn_mfma_f32_16x16x32_bf16(af[mi], bf[ni], acc[mi][ni], 0, 0, 0);
            }
        }
        #pragma unroll
        for (int mi = 0; mi < 4; mi++)
            #pragma unroll
            for (int ni = 0; ni < 4; ni++) {
                int col = n0 + wn + ni * 16 + l16;
                #pragma unroll
                for (int r = 0; r < 4; r++) {
                    int row = m0 + wm + mi * 16 + quad * 4 + r;
                    Qp[(size_t)row * C_ + col] = f2bf(acc[mi][ni][r] * CS_);
                }
            }
        return;
    }

    // ---------------- kvproj path ----------------
    {
        short* As = lds;            // 32 x 64 bf16, frag order (2048)
        short* Bs = lds + 2048;     // 64 x 64 bf16, frag order (4096)
        int idx2 = bx - 512;
        int mode = idx2 >> 8;
        int m0 = (idx2 & 255) * 32;
        const float* A  = mode ? Vsrc : Ksrc;
        const short* Bt = mode ? WvT : WkT;
        short* Out      = mode ? Vfo : Kfo;

        int wrow = (w >> 1) * 16, wcol = (w & 1) * 32;

        int arow = tid >> 3, acol = (tid & 7) * 8;
        int akh = acol >> 5, aoct = (acol >> 3) & 3;
        short* asl = As + ((((arow >> 4) * 2 + akh) * 64 + (arow & 15) * 4 + aoct) * 8);
        const float* ag = A + (size_t)(m0 + arow) * C_ + acol;
        int brow = tid >> 2, bcol = (tid & 3) * 16;
        int bkh = bcol >> 5, boct = (bcol >> 3) & 3;
        short* bsl = Bs + ((((brow >> 4) * 2 + bkh) * 64 + (brow & 15) * 4 + boct) * 8);
        const short* bg = Bt + (size_t)brow * C_ + bcol;

        // early-issue reg prefetch, same pattern as qproj
        float4 fa = *(const float4*)(ag);
        float4 fb = *(const float4*)(ag + 4);
        uint4 t0 = *(const uint4*)(bg);
        uint4 t1 = *(const uint4*)(bg + 8);

        f32x4 acc[2] = {};
        for (int k0 = 0; k0 < C_; k0 += 64) {
            __syncthreads();
            {
                uint4 pa; pa.x = pk2(fa.x,fa.y); pa.y = pk2(fa.z,fa.w);
                          pa.z = pk2(fb.x,fb.y); pa.w = pk2(fb.z,fb.w);
                *(uint4*)asl = pa;
                *(uint4*)bsl = t0; *(uint4*)(bsl + 8) = t1;
            }
            if (k0 + 64 < C_) {
                fa = *(const float4*)(ag + k0 + 64);
                fb = *(const float4*)(ag + k0 + 68);
                t0 = *(const uint4*)(bg + k0 + 64);
                t1 = *(const uint4*)(bg + k0 + 72);
            }
            __syncthreads();
            #pragma unroll
            for (int ks = 0; ks < 2; ks++) {
                bfrag af = *(const bfrag*)(As + (((wrow >> 4) * 2 + ks) * 64 + l16 * 4 + quad) * 8);
                #pragma unroll
                for (int ni = 0; ni < 2; ni++) {
                    int n = wcol + ni * 16;
                    bfrag bf = *(const bfrag*)(Bs + (((n >> 4) * 2 + ks) * 64 + l16 * 4 + quad) * 8);
                    acc[ni] = __builtin_amdgcn_mfma_f32_16x16x32_bf16(af, bf, acc[ni], 0, 0, 0);
                }
            }
        }
        if (mode == 0) {
            #pragma unroll
            for (int ni = 0; ni < 2; ni++)
                #pragma unroll
                for (int r = 0; r < 4; r++) {
                    int key = m0 + wrow + quad * 4 + r;
                    int d = wcol + ni * 16 + l16;
                    size_t adr = (size_t)(key >> 6) * 4096 +
                        ((((d >> 5) * 4 + ((key >> 4) & 3)) * 4 + ((d >> 3) & 3)) * 16 + (key & 15)) * 8 + (d & 7);
                    Out[adr] = f2bf(acc[ni][r]);
                }
        } else {
            #pragma unroll
            for (int ni = 0; ni < 2; ni++) {
                int ni2 = (w & 1) * 2 + ni;
                int key = m0 + wrow + quad * 4;
                int tile = key >> 6, kfk = (key >> 5) & 1, qv = (key >> 3) & 3;
                int jb = (quad & 1) * 4;
                uint2 pk; pk.x = pk2(acc[ni][0], acc[ni][1]); pk.y = pk2(acc[ni][2], acc[ni][3]);
                *(uint2*)(Out + (size_t)tile * 4096 + (((kfk * 4 + ni2) * 4 + qv) * 16 + l16) * 8 + jb) = pk;
            }
        }
    }
}

// ---------------- attention: 2 heads/block, 8 waves, 2 blocks/CU -----------
__global__ __launch_bounds__(512, 4) void attn_kernel(
    const short* __restrict__ Qp, const short* __restrict__ Kfo,
    const short* __restrict__ Vfo, short* __restrict__ Out)
{
    // 64 KB: KV dbuf 2x8192 shorts @ [0,16384); Ps 8 waves x 2048 shorts
    __shared__ __align__(16) short lds[32768];
    int qb = blockIdx.x, hg = blockIdx.y, b = blockIdx.z;
    int tid = threadIdx.x, w = tid >> 6, lane = tid & 63;
    int quad = lane >> 4, l16 = lane & 15;
    int h = hg * 2 + (w >> 2);          // wave's head
    int wq = (w & 3) * 32;              // wave's q-row offset within 128
    short* Ps = lds + 16384 + w * 2048;
    int m0q = b * T_ + qb * 128;

    // qf straight from global: B-frag element e <-> consecutive d
    bfrag qf[2][2];
    #pragma unroll
    for (int nb = 0; nb < 2; nb++)
        #pragma unroll
        for (int kf = 0; kf < 2; kf++)
            qf[nb][kf] = *(const bfrag*)(Qp +
                (size_t)(m0q + wq + nb * 16 + l16) * C_ + h * 64 + kf * 32 + quad * 8);

    const short* Kb = Kfo + (size_t)b * (T_ * D_);
    const short* Vb = Vfo + (size_t)b * (T_ * D_);
    int q0 = qb * 128 + wq;

    f32x4 o[4][2] = {};
    f32x4 lacc[2] = {};                 // softmax denom via MFMA ones-trick
    bfrag ones;
    #pragma unroll
    for (int e = 0; e < 8; e++) ones[e] = (short)0x3F80;   // bf16 1.0

    int fragoff = (quad * 16 + l16) * 8;
    int st8 = tid * 8;                  // 512 thr x 8 shorts = one 4096 tile

    // prologue: stage tile 0 (K into [0,4096), V into [4096,8192))
    GLL16(Kb + st8, lds + st8);
    GLL16(Vb + st8, lds + 4096 + st8);
    __syncthreads();

    for (int t = 0; t < T_ / 64; t++) {
        short* bc = lds + (t & 1) * 8192;
        if (t + 1 < T_ / 64) {            // prefetch next tile into other buf
            short* bn = lds + ((t + 1) & 1) * 8192;
            GLL16(Kb + (t + 1) * 4096 + st8, bn + st8);
            GLL16(Vb + (t + 1) * 4096 + st8, bn + 4096 + st8);
        }
        bfrag ka[2][4];
        #pragma unroll
        for (int kf = 0; kf < 2; kf++)
            #pragma unroll
            for (int mi = 0; mi < 4; mi++)
                ka[kf][mi] = *(const bfrag*)(bc + (kf * 4 + mi) * 512 + fragoff);
        f32x4 s[4][2];
        #pragma unroll
        for (int mi = 0; mi < 4; mi++)
            #pragma unroll
            for (int nb = 0; nb < 2; nb++) {
                f32x4 z = {};
                z = __builtin_amdgcn_mfma_f32_16x16x32_bf16(ka[0][mi], qf[nb][0], z, 0, 0, 0);
                s[mi][nb] = __builtin_amdgcn_mfma_f32_16x16x32_bf16(ka[1][mi], qf[nb][1], z, 0, 0, 0);
            }
        bfrag va[2][4];
        #pragma unroll
        for (int kf = 0; kf < 2; kf++)
            #pragma unroll
            for (int mi = 0; mi < 4; mi++)
                va[kf][mi] = *(const bfrag*)(bc + 4096 + (kf * 4 + mi) * 512 + fragoff);
        #pragma unroll
        for (int nb = 0; nb < 2; nb++) {
            #pragma unroll
            for (int mi = 0; mi < 4; mi++) {
                float p0 = EXP2(s[mi][nb][0]);
                float p1 = EXP2(s[mi][nb][1]);
                float p2 = EXP2(s[mi][nb][2]);
                float p3 = EXP2(s[mi][nb][3]);
                uint2 pk; pk.x = pk2(p0, p1); pk.y = pk2(p2, p3);
                int kf = mi >> 1, qp_ = (mi & 1) * 2 + (quad >> 1), jb = (quad & 1) * 4;
                *(uint2*)(Ps + (kf * 2 + nb) * 512 + qp_ * 128 + l16 * 8 + jb) = pk;
            }
        }
        #pragma unroll
        for (int nb = 0; nb < 2; nb++) {
            bfrag pf0 = *(const bfrag*)(Ps + (0 + nb) * 512 + quad * 128 + l16 * 8);
            bfrag pf1 = *(const bfrag*)(Ps + (2 + nb) * 512 + quad * 128 + l16 * 8);
            #pragma unroll
            for (int mi = 0; mi < 4; mi++) {
                o[mi][nb] = __builtin_amdgcn_mfma_f32_16x16x32_bf16(va[0][mi], pf0, o[mi][nb], 0, 0, 0);
                o[mi][nb] = __builtin_amdgcn_mfma_f32_16x16x32_bf16(va[1][mi], pf1, o[mi][nb], 0, 0, 0);
            }
            lacc[nb] = __builtin_amdgcn_mfma_f32_16x16x32_bf16(ones, pf0, lacc[nb], 0, 0, 0);
            lacc[nb] = __builtin_amdgcn_mfma_f32_16x16x32_bf16(ones, pf1, lacc[nb], 0, 0, 0);
        }
        __syncthreads();   // prefetch landed; all waves done with bc
    }
    #pragma unroll
    for (int nb = 0; nb < 2; nb++) {
        float rl = 1.0f / lacc[nb][0];   // every C row = full column sum
        size_t row = (size_t)(b * T_ + q0 + nb * 16 + l16);
        #pragma unroll
        for (int mi = 0; mi < 4; mi++) {
            uint2 pk; pk.x = pk2(o[mi][nb][0] * rl, o[mi][nb][1] * rl);
                      pk.y = pk2(o[mi][nb][2] * rl, o[mi][nb][3] * rl);
            *(uint2*)(Out + row * C_ + h * 64 + mi * 16 + quad * 4) = pk;
        }
    }
}

// ---------------- final GEMM, 128x128 tile, BK=64, m on grid.x (XCD) -------
__global__ __launch_bounds__(256) void gemm_fin_kernel(
    const short* __restrict__ A, const short* __restrict__ Bt,
    const float* __restrict__ bias, float* __restrict__ Out)
{
    __shared__ __align__(16) short As[8192];   // 128 x 64, frag order
    __shared__ __align__(16) short Bs[8192];   // 128 x 64, frag order
    const int N = C_, K = C_;
    int tid = threadIdx.x, w = tid >> 6, lane = tid & 63;
    int quad = lane >> 4, l16 = lane & 15;
    int wm = (w >> 1) * 64, wn = (w & 1) * 64;
    // XCD-locality: same-A blocks (same m0) spaced 64 apart -> same XCD.
    int m0 = blockIdx.x * 128, n0 = blockIdx.y * 128;

    const short* gA[4]; short* lA[4];
    const short* gB[4]; short* lB[4];
    #pragma unroll
    for (int i = 0; i < 4; i++) {
        int c = tid + 256 * i;
        int row = ((c >> 7) << 4) + ((c & 63) >> 2);
        int koff = ((c >> 6) & 1) * 32 + (c & 3) * 8;
        gA[i] = A + (size_t)(m0 + row) * K + koff;
        lA[i] = As + c * 8;
        gB[i] = Bt + (size_t)(n0 + row) * K + koff;
        lB[i] = Bs + c * 8;
    }

    f32x4 acc[4][4] = {};
    for (int k0 = 0; k0 < K; k0 += 64) {
        __syncthreads();
        #pragma unroll
        for (int i = 0; i < 4; i++) GLL16(gA[i] + k0, lA[i]);
        #pragma unroll
        for (int i = 0; i < 4; i++) GLL16(gB[i] + k0, lB[i]);
        __syncthreads();
        #pragma unroll
        for (int ks = 0; ks < 2; ks++) {
            bfrag af[4], bf[4];
            #pragma unroll
            for (int i = 0; i < 4; i++)
                af[i] = *(const bfrag*)(As + ((((wm >> 4) + i) * 2 + ks) * 64 + l16 * 4 + quad) * 8);
            #pragma unroll
            for (int i = 0; i < 4; i++)
                bf[i] = *(const bfrag*)(Bs + ((((wn >> 4) + i) * 2 + ks) * 64 + l16 * 4 + quad) * 8);
            #pragma unroll
            for (int mi = 0; mi < 4; mi++)
                #pragma unroll
                for (int ni = 0; ni < 4; ni++)
                    acc[mi][ni] = __builtin_amdgcn_mfma_f32_16x16x32_bf16(af[mi], bf[ni], acc[mi][ni], 0, 0, 0);
        }
    }
    #pragma unroll
    for (int mi = 0; mi < 4; mi++)
        #pragma unroll
        for (int ni = 0; ni < 4; ni++) {
            int col = n0 + wn + ni * 16 + l16;
            float bv = bias[col];
            #pragma unroll
            for (int r = 0; r < 4; r++) {
                int row = m0 + wm + mi * 16 + quad * 4 + r;
                Out[(size_t)row * N + col] = acc[mi][ni][r] + bv;
            }
        }
}

extern "C" void kernel_launch(void* const* d_in, const int* in_sizes, int n_in,
                              void* d_out, int out_size, void* d_ws, size_t ws_size,
                              hipStream_t stream) {
    const float* q  = (const float*)d_in[0];
    const float* k  = (const float*)d_in[1];
    const float* v  = (const float*)d_in[2];
    const float* Wq = (const float*)d_in[3];
    const float* Wk = (const float*)d_in[4];
    const float* Wv = (const float*)d_in[5];
    const float* Wp = (const float*)d_in[6];
    const float* bp = (const float*)d_in[7];
    float* out = (float*)d_out;

    char* ws = (char*)d_ws;
    short* Qp       = (short*)(ws);                   // 16 MB [BT][C] bf16, pre-scaled
    short* attn_out = (short*)(ws + (16u << 20));     // 16 MB [BT][C]
    short* WqT  = (short*)(ws + (32u << 20));         //  2 MB
    short* WpT  = (short*)(ws + (34u << 20));         //  2 MB
    short* Kfo  = (short*)(ws + (36u << 20));         //  1 MB
    short* Vfo  = (short*)(ws + (37u << 20));         //  1 MB
    short* WkT  = (short*)(ws + (38u << 20));         // 128 KB
    short* WvT  = (short*)(ws + (38u << 20) + (1u << 18));

    dim3 blk(256);
    prep_kernel<<<544, blk, 0, stream>>>(Wq, Wk, Wv, Wp, WqT, WkT, WvT, WpT);
    proj_kernel<<<1024, blk, 0, stream>>>(q, k, v, WqT, WkT, WvT, Qp, Kfo, Vfo);
    attn_kernel<<<dim3(16, 8, 4), dim3(512), 0, stream>>>(Qp, Kfo, Vfo, attn_out);
    gemm_fin_kernel<<<dim3(64, 8), blk, 0, stream>>>(attn_out, WpT, bp, out);
}